// Round 5
// baseline (1140.201 us; speedup 1.0000x reference)
//
#include <hip/hip_runtime.h>

#define V_N 30522
#define A_N 2
#define H_N 128
#define O_N 16
#define B_N 8
#define D_N 256
#define NNZ_N 250000
#define NNZ_T (A_N * NNZ_N)  // 500000
#define M_N (B_N * D_N)      // 2048

#define BM 64
#define BK 32
#define KSPLIT 8
#define KC ((V_N + KSPLIT - 1) / KSPLIT)  // 3816

typedef __attribute__((ext_vector_type(8))) short bf16x8_t;
typedef __attribute__((ext_vector_type(4))) float f32x4_t;

static __device__ __forceinline__ unsigned short f2bf(float f) {
    union { float f; unsigned u; } v; v.f = f;
    unsigned r = v.u + 0x7fffu + ((v.u >> 16) & 1u);   // RNE
    return (unsigned short)(r >> 16);
}

// ---------------- Step 1: histogram of row indices ----------------
__global__ __launch_bounds__(256) void hist_kernel(const int* __restrict__ rows,
                                                   int* __restrict__ count) {
    int n = blockIdx.x * blockDim.x + threadIdx.x;
    if (n >= NNZ_T) return;
    atomicAdd(&count[rows[n]], 1);
}

// ---------------- Step 2: exclusive prefix scan (single block, R2-verified) -------------
__global__ __launch_bounds__(1024) void scan_kernel(const int* __restrict__ count,
                                                    int* __restrict__ row_start,
                                                    int* __restrict__ cursor) {
    __shared__ int sdata[1024];
    __shared__ int carry;
    if (threadIdx.x == 0) carry = 0;
    __syncthreads();
    for (int base = 0; base < V_N; base += 1024) {
        int i = base + threadIdx.x;
        int v = (i < V_N) ? count[i] : 0;
        sdata[threadIdx.x] = v;
        __syncthreads();
        for (int off = 1; off < 1024; off <<= 1) {
            int t = (threadIdx.x >= off) ? sdata[threadIdx.x - off] : 0;
            __syncthreads();
            sdata[threadIdx.x] += t;
            __syncthreads();
        }
        int exc = sdata[threadIdx.x] - v + carry;
        if (i < V_N) { row_start[i] = exc; cursor[i] = exc; }
        __syncthreads();
        if (threadIdx.x == 1023) carry += sdata[1023];
        __syncthreads();
    }
    if (threadIdx.x == 0) row_start[V_N] = carry;
}

// ---------------- Step 3: scatter nnz into row-sorted order ----------------
__global__ __launch_bounds__(256) void scatter_kernel(const int* __restrict__ rows,
                                                      const int* __restrict__ cols,
                                                      const float* __restrict__ vals,
                                                      int* __restrict__ cursor,
                                                      int* __restrict__ sorted_colp,
                                                      float* __restrict__ sorted_val) {
    int n = blockIdx.x * blockDim.x + threadIdx.x;
    if (n >= NNZ_T) return;
    int a = n / NNZ_N;
    int r = rows[n];
    int pos = atomicAdd(&cursor[r], 1);
    sorted_colp[pos] = a * V_N + cols[n];
    sorted_val[pos] = vals[n];
}

// ---------------- Step 4: segmented accumulate -> h_sum f32 [V][128] (R2-verified) ------
__global__ __launch_bounds__(256) void accum_kernel(const int* __restrict__ row_start,
                                                    const int* __restrict__ sorted_colp,
                                                    const float* __restrict__ sorted_val,
                                                    const float* __restrict__ W,
                                                    float* __restrict__ h_sum) {
    long long gid = (long long)blockIdx.x * blockDim.x + threadIdx.x;
    if (gid >= (long long)V_N * 32) return;
    int row = (int)(gid >> 5);
    int chunk = (int)(gid & 31);
    int s = row_start[row];
    int e = row_start[row + 1];
    float4 acc = make_float4(0.f, 0.f, 0.f, 0.f);
    for (int i = s; i < e; ++i) {
        int cp = sorted_colp[i];
        float v = sorted_val[i];
        const float4 w = *reinterpret_cast<const float4*>(
            W + (long long)cp * H_N + chunk * 4);
        acc.x += v * w.x;
        acc.y += v * w.y;
        acc.z += v * w.z;
        acc.w += v * w.w;
    }
    *reinterpret_cast<float4*>(h_sum + (long long)row * H_N + chunk * 4) = acc;
}

// ---------------- Step 5: GEMM with MFMA core, LDS-staged bf16 tiles --------------------
// grid (M_N/BM=32, KSPLIT=8), 256 threads = 4 waves; wave w owns rows [w*16, w*16+16)
__global__ __launch_bounds__(256) void gemm_mfma2(const float* __restrict__ X,
                                                  const float* __restrict__ Hs,
                                                  float* __restrict__ fused) {
    __shared__ __align__(16) short xs[BM][BK];        // 4 KB: X tile, bf16, [row][k]
    __shared__ __align__(16) short hsT[H_N][BK];      // 8 KB: h tile, bf16, [col][k]
    const int tid = threadIdx.x;
    const int w = tid >> 6;
    const int lane = tid & 63;
    const int l15 = lane & 15;
    const int kg = lane >> 4;  // 0..3
    const int row0 = blockIdx.x * BM;
    const int k0 = blockIdx.y * KC;
    const int kend = min(V_N, k0 + KC);

    f32x4_t acc[8] = {};

    for (int kb = k0; kb < kend; kb += BK) {
        // stage X tile 64x32 -> bf16
        for (int idx = tid; idx < BM * BK; idx += 256) {
            int r = idx >> 5, k2 = idx & 31;
            int gk = kb + k2;
            float xv = (gk < kend) ? X[(size_t)(row0 + r) * V_N + gk] : 0.f;
            xs[r][k2] = (short)f2bf(xv);
        }
        // stage h tile 32x128 -> bf16, k-transposed in LDS
        for (int idx = tid; idx < BK * H_N; idx += 256) {
            int k2 = idx >> 7, c = idx & 127;
            int gk = kb + k2;
            float hv = (gk < kend) ? Hs[(size_t)gk * H_N + c] : 0.f;
            hsT[c][k2] = (short)f2bf(hv);
        }
        __syncthreads();
        // A-frag: row=l&15 (wave-local rows w*16+l15), k=(l>>4)*8+j contiguous
        bf16x8_t av = *reinterpret_cast<const bf16x8_t*>(&xs[w * 16 + l15][kg * 8]);
#pragma unroll
        for (int n = 0; n < 8; ++n) {
            bf16x8_t bv = *reinterpret_cast<const bf16x8_t*>(&hsT[n * 16 + l15][kg * 8]);
            acc[n] = __builtin_amdgcn_mfma_f32_16x16x32_bf16(av, bv, acc[n], 0, 0, 0);
        }
        __syncthreads();
    }

    // D layout (m89/m91): col=lane&15, row=(lane>>4)*4+reg
#pragma unroll
    for (int n = 0; n < 8; ++n)
#pragma unroll
        for (int r4 = 0; r4 < 4; ++r4)
            atomicAdd(&fused[(size_t)(row0 + w * 16 + kg * 4 + r4) * H_N + n * 16 + l15],
                      acc[n][r4]);
}

// ---------------- Step 6: FC epilogue (R2-verified) ----------------
__global__ __launch_bounds__(256) void fc_kernel(const float* __restrict__ fused,
                                                 const float* __restrict__ fcW,
                                                 const float* __restrict__ fcb,
                                                 float* __restrict__ out) {
    int idx = blockIdx.x * blockDim.x + threadIdx.x;
    if (idx >= M_N * O_N) return;
    int row = idx >> 4;
    int o = idx & 15;
    float s = fcb[o];
    const float* f = fused + (long long)row * H_N;
#pragma unroll
    for (int h = 0; h < H_N; ++h) s += f[h] * fcW[h * O_N + o];
    out[idx] = s;
}

extern "C" void kernel_launch(void* const* d_in, const int* in_sizes, int n_in,
                              void* d_out, int out_size, void* d_ws, size_t ws_size,
                              hipStream_t stream) {
    const float* x    = (const float*)d_in[0];
    const int* rows   = (const int*)d_in[1];
    const int* cols   = (const int*)d_in[2];
    const float* vals = (const float*)d_in[3];
    const float* W    = (const float*)d_in[4];
    const float* fcW  = (const float*)d_in[5];
    const float* fcb  = (const float*)d_in[6];
    float* out = (float*)d_out;

    // R2-proven workspace layout (~21.07 MB, no aliasing)
    float* h_sum      = (float*)d_ws;                         // V*H f32
    float* fused      = h_sum + (size_t)V_N * H_N;            // M*H f32
    int*   count      = (int*)(fused + (size_t)M_N * H_N);    // V
    int*   row_start  = count + V_N;                          // V+1
    int*   cursor     = row_start + V_N + 1;                  // V
    int*   sorted_colp= cursor + V_N;                         // NNZ_T
    float* sorted_val = (float*)(sorted_colp + NNZ_T);        // NNZ_T

    size_t zero_bytes = ((size_t)M_N * H_N) * sizeof(float) + (size_t)V_N * sizeof(int);
    hipMemsetAsync(fused, 0, zero_bytes, stream);

    hist_kernel<<<(NNZ_T + 255) / 256, 256, 0, stream>>>(rows, count);
    scan_kernel<<<1, 1024, 0, stream>>>(count, row_start, cursor);
    scatter_kernel<<<(NNZ_T + 255) / 256, 256, 0, stream>>>(rows, cols, vals, cursor,
                                                            sorted_colp, sorted_val);
    {
        long long total = (long long)V_N * 32;
        accum_kernel<<<(int)((total + 255) / 256), 256, 0, stream>>>(
            row_start, sorted_colp, sorted_val, W, h_sum);
    }

    gemm_mfma2<<<dim3(M_N / BM, KSPLIT), 256, 0, stream>>>(x, h_sum, fused);

    fc_kernel<<<(M_N * O_N + 255) / 256, 256, 0, stream>>>(fused, fcW, fcb, out);
}

// Round 6
// 338.075 us; speedup vs baseline: 3.3726x; 3.3726x over previous
//
#include <hip/hip_runtime.h>

#define V_N 30522
#define A_N 2
#define H_N 128
#define O_N 16
#define B_N 8
#define D_N 256
#define NNZ_N 250000
#define NNZ_T (A_N * NNZ_N)  // 500000
#define M_N (B_N * D_N)      // 2048

#define KPAD 30720
#define BM 64
#define BK 32
#define KSPL 16
#define KC (KPAD / KSPL)     // 1920 = 60 steps of 32

typedef __attribute__((ext_vector_type(8))) short bf16x8_t;
typedef __attribute__((ext_vector_type(4))) float f32x4_t;

static __device__ __forceinline__ unsigned short f2bf(float f) {
    union { float f; unsigned u; } v; v.f = f;
    unsigned r = v.u + 0x7fffu + ((v.u >> 16) & 1u);   // RNE
    return (unsigned short)(r >> 16);
}

// ---------------- Step 1: histogram of row indices (R2-verified) ----------------
__global__ __launch_bounds__(256) void hist_kernel(const int* __restrict__ rows,
                                                   int* __restrict__ count) {
    int n = blockIdx.x * blockDim.x + threadIdx.x;
    if (n >= NNZ_T) return;
    atomicAdd(&count[rows[n]], 1);
}

// ---------------- Step 2: exclusive prefix scan (R2-verified) ----------------
__global__ __launch_bounds__(1024) void scan_kernel(const int* __restrict__ count,
                                                    int* __restrict__ row_start,
                                                    int* __restrict__ cursor) {
    __shared__ int sdata[1024];
    __shared__ int carry;
    if (threadIdx.x == 0) carry = 0;
    __syncthreads();
    for (int base = 0; base < V_N; base += 1024) {
        int i = base + threadIdx.x;
        int v = (i < V_N) ? count[i] : 0;
        sdata[threadIdx.x] = v;
        __syncthreads();
        for (int off = 1; off < 1024; off <<= 1) {
            int t = (threadIdx.x >= off) ? sdata[threadIdx.x - off] : 0;
            __syncthreads();
            sdata[threadIdx.x] += t;
            __syncthreads();
        }
        int exc = sdata[threadIdx.x] - v + carry;
        if (i < V_N) { row_start[i] = exc; cursor[i] = exc; }
        __syncthreads();
        if (threadIdx.x == 1023) carry += sdata[1023];
        __syncthreads();
    }
    if (threadIdx.x == 0) row_start[V_N] = carry;
}

// ---------------- Step 3: scatter nnz into row-sorted order (R2-verified) ----------------
__global__ __launch_bounds__(256) void scatter_kernel(const int* __restrict__ rows,
                                                      const int* __restrict__ cols,
                                                      const float* __restrict__ vals,
                                                      int* __restrict__ cursor,
                                                      int* __restrict__ sorted_colp,
                                                      float* __restrict__ sorted_val) {
    int n = blockIdx.x * blockDim.x + threadIdx.x;
    if (n >= NNZ_T) return;
    int a = n / NNZ_N;
    int r = rows[n];
    int pos = atomicAdd(&cursor[r], 1);
    sorted_colp[pos] = a * V_N + cols[n];
    sorted_val[pos] = vals[n];
}

// ---------------- Step 4: segmented accumulate -> h_t bf16 [128][KPAD] (k-major) --------
// thread (row=k, chunk): 4 scattered 2B stores h_t[4*chunk+j][row]. Pad pre-zeroed by memset.
__global__ __launch_bounds__(256) void accum_kernel(const int* __restrict__ row_start,
                                                    const int* __restrict__ sorted_colp,
                                                    const float* __restrict__ sorted_val,
                                                    const float* __restrict__ W,
                                                    short* __restrict__ h_t) {
    long long gid = (long long)blockIdx.x * blockDim.x + threadIdx.x;
    if (gid >= (long long)V_N * 32) return;
    int row = (int)(gid >> 5);
    int chunk = (int)(gid & 31);
    int s = row_start[row];
    int e = row_start[row + 1];
    float4 acc = make_float4(0.f, 0.f, 0.f, 0.f);
    for (int i = s; i < e; ++i) {
        int cp = sorted_colp[i];
        float v = sorted_val[i];
        const float4 w = *reinterpret_cast<const float4*>(
            W + (long long)cp * H_N + chunk * 4);
        acc.x += v * w.x;
        acc.y += v * w.y;
        acc.z += v * w.z;
        acc.w += v * w.w;
    }
    h_t[(size_t)(chunk * 4 + 0) * KPAD + row] = (short)f2bf(acc.x);
    h_t[(size_t)(chunk * 4 + 1) * KPAD + row] = (short)f2bf(acc.y);
    h_t[(size_t)(chunk * 4 + 2) * KPAD + row] = (short)f2bf(acc.z);
    h_t[(size_t)(chunk * 4 + 3) * KPAD + row] = (short)f2bf(acc.w);
}

// ---------------- Step 5: MFMA GEMM. X staged LDS f32->bf16; B direct from global h_t ----
// grid (32, KSPL), 512 thr = 8 waves: wave = (wm = wid>>1 rows, wc = wid&1 col-half)
__global__ __launch_bounds__(512) void gemm_mfma3(const float* __restrict__ X,
                                                  const short* __restrict__ h_t,
                                                  float* __restrict__ partials) {
    __shared__ short xs[BM][40];   // pad 40 shorts: b128 reads stay 16B-aligned, ~2-way banks
    const int tid = threadIdx.x;
    const int wid = tid >> 6;
    const int wm = wid >> 1;        // 0..3 : rows wm*16..+15
    const int wc = wid & 1;         // 0..1 : cols wc*64..+63
    const int lane = tid & 63;
    const int l15 = lane & 15;
    const int kg = lane >> 4;       // 0..3
    const int row0 = blockIdx.x * BM;
    const int ks = blockIdx.y;
    const int k0 = ks * KC;

    // staging role: thread -> (r, c4), one float4-worth per K-step
    const int sr = tid >> 3;            // 0..63
    const int sc4 = (tid & 7) * 4;      // 0,4,...,28
    const float* xptr = X + (size_t)(row0 + sr) * V_N;

    f32x4_t acc[4] = {};

    for (int kb = k0; kb < k0 + KC; kb += BK) {
        int gk = kb + sc4;
        float a[4];
        if (gk + 3 < V_N) {
            const float2* p = reinterpret_cast<const float2*>(xptr + gk);
            float2 u = p[0], v = p[1];
            a[0] = u.x; a[1] = u.y; a[2] = v.x; a[3] = v.y;
        } else {
#pragma unroll
            for (int j = 0; j < 4; ++j) a[j] = (gk + j < V_N) ? xptr[gk + j] : 0.f;
        }
        short4 s4;
        s4.x = (short)f2bf(a[0]); s4.y = (short)f2bf(a[1]);
        s4.z = (short)f2bf(a[2]); s4.w = (short)f2bf(a[3]);
        *reinterpret_cast<short4*>(&xs[sr][sc4]) = s4;
        __syncthreads();

        // A-frag (R5-verified): row = wm*16+l15, k = kg*8+j contiguous
        bf16x8_t av = *reinterpret_cast<const bf16x8_t*>(&xs[wm * 16 + l15][kg * 8]);
#pragma unroll
        for (int n = 0; n < 4; ++n) {
            // B-frag (R5-verified layout, global k-major h_t): col = wc*64+n*16+l15
            bf16x8_t bv = *reinterpret_cast<const bf16x8_t*>(
                h_t + (size_t)(wc * 64 + n * 16 + l15) * KPAD + kb + kg * 8);
            acc[n] = __builtin_amdgcn_mfma_f32_16x16x32_bf16(av, bv, acc[n], 0, 0, 0);
        }
        __syncthreads();
    }

    // D layout (R5-verified): col = l15, row = kg*4 + r4. Unique slice per block -> plain stores.
#pragma unroll
    for (int n = 0; n < 4; ++n)
#pragma unroll
        for (int r4 = 0; r4 < 4; ++r4)
            partials[((size_t)ks * M_N + row0 + wm * 16 + kg * 4 + r4) * H_N
                     + wc * 64 + n * 16 + l15] = acc[n][r4];
}

// ---------------- Step 6: FC epilogue with split-K reduce ----------------
__global__ __launch_bounds__(256) void fc_kernel(const float* __restrict__ partials,
                                                 const float* __restrict__ fcW,
                                                 const float* __restrict__ fcb,
                                                 float* __restrict__ out) {
    __shared__ float frow[16][128];
    int row0 = blockIdx.x * 16;
    for (int e = threadIdx.x; e < 16 * 128; e += 256) {
        int r = e >> 7, c = e & 127;
        float s = 0.f;
#pragma unroll
        for (int w = 0; w < KSPL; ++w)
            s += partials[((size_t)w * M_N + row0 + r) * H_N + c];
        frow[r][c] = s;
    }
    __syncthreads();
    int r = threadIdx.x >> 4, o = threadIdx.x & 15;
    float s = fcb[o];
#pragma unroll
    for (int h = 0; h < H_N; ++h) s += frow[r][h] * fcW[h * O_N + o];
    out[(size_t)(row0 + r) * O_N + o] = s;
}

extern "C" void kernel_launch(void* const* d_in, const int* in_sizes, int n_in,
                              void* d_out, int out_size, void* d_ws, size_t ws_size,
                              hipStream_t stream) {
    const float* x    = (const float*)d_in[0];
    const int* rows   = (const int*)d_in[1];
    const int* cols   = (const int*)d_in[2];
    const float* vals = (const float*)d_in[3];
    const float* W    = (const float*)d_in[4];
    const float* fcW  = (const float*)d_in[5];
    const float* fcb  = (const float*)d_in[6];
    float* out = (float*)d_out;

    // ws layout: [h_t 7.86MB][union: CSR 4.37MB | partials 16.78MB] = 24.64 MB total.
    // CSR is dead after accum; gemm (later on same stream) overwrites it with partials.
    char* base = (char*)d_ws;
    short* h_t = (short*)base;                                   // 128*KPAD bf16
    size_t o_union = ((size_t)H_N * KPAD * 2 + 255) & ~(size_t)255;
    size_t c = o_union;
    auto calloc2 = [&](size_t bytes) { size_t p = c; c = (c + bytes + 255) & ~(size_t)255; return p; };
    size_t o_count  = calloc2((size_t)V_N * 4);
    size_t o_rstart = calloc2((size_t)(V_N + 1) * 4);
    size_t o_cursor = calloc2((size_t)V_N * 4);
    size_t o_scolp  = calloc2((size_t)NNZ_T * 4);
    size_t o_sval   = calloc2((size_t)NNZ_T * 4);

    int*   count      = (int*)(base + o_count);
    int*   row_start  = (int*)(base + o_rstart);
    int*   cursor     = (int*)(base + o_cursor);
    int*   sorted_colp= (int*)(base + o_scolp);
    float* sorted_val = (float*)(base + o_sval);
    float* partials   = (float*)(base + o_union);                // KSPL*M*H f32

    hipMemsetAsync(h_t, 0, (size_t)H_N * KPAD * 2, stream);      // zero incl. K-pad
    hipMemsetAsync(count, 0, (size_t)V_N * 4, stream);

    hist_kernel<<<(NNZ_T + 255) / 256, 256, 0, stream>>>(rows, count);
    scan_kernel<<<1, 1024, 0, stream>>>(count, row_start, cursor);
    scatter_kernel<<<(NNZ_T + 255) / 256, 256, 0, stream>>>(rows, cols, vals, cursor,
                                                            sorted_colp, sorted_val);
    {
        long long total = (long long)V_N * 32;
        accum_kernel<<<(int)((total + 255) / 256), 256, 0, stream>>>(
            row_start, sorted_colp, sorted_val, W, h_t);
    }

    gemm_mfma3<<<dim3(M_N / BM, KSPL), 512, 0, stream>>>(x, h_t, partials);

    fc_kernel<<<M_N / 16, 256, 0, stream>>>(partials, fcW, fcb, out);
}

// Round 7
// 199.554 us; speedup vs baseline: 5.7137x; 1.6941x over previous
//
#include <hip/hip_runtime.h>

#define V_N 30522
#define A_N 2
#define H_N 128
#define O_N 16
#define NNZ_N 250000
#define NNZ_T (A_N * NNZ_N)  // 500000
#define M_N 2048

#define KPAD 30720
#define KSPL 32
#define KC (KPAD / KSPL)     // 960 = 30 steps of 32
#define NCHUNK 30            // ceil(V_N / 1024)

typedef __attribute__((ext_vector_type(8))) short bf16x8_t;
typedef __attribute__((ext_vector_type(4))) float f32x4_t;

static __device__ __forceinline__ unsigned short f2bf(float f) {
    union { float f; unsigned u; } v; v.f = f;
    unsigned r = v.u + 0x7fffu + ((v.u >> 16) & 1u);   // RNE
    return (unsigned short)(r >> 16);
}

// ---------------- Step 1: histogram of row indices (R2-verified) ----------------
__global__ __launch_bounds__(256) void hist_kernel(const int* __restrict__ rows,
                                                   int* __restrict__ count) {
    int n = blockIdx.x * blockDim.x + threadIdx.x;
    if (n >= NNZ_T) return;
    atomicAdd(&count[rows[n]], 1);
}

// ---------------- Step 2a: per-1024-chunk sums ----------------
__global__ __launch_bounds__(1024) void scanA_kernel(const int* __restrict__ count,
                                                     int* __restrict__ csum) {
    __shared__ int sdata[1024];
    int tid = threadIdx.x;
    int i = blockIdx.x * 1024 + tid;
    sdata[tid] = (i < V_N) ? count[i] : 0;
    __syncthreads();
    for (int off = 512; off > 0; off >>= 1) {
        if (tid < off) sdata[tid] += sdata[tid + off];
        __syncthreads();
    }
    if (tid == 0) csum[blockIdx.x] = sdata[0];
}

// ---------------- Step 2b: scan chunk sums (serial, 30 values) ----------------
__global__ void scanB_kernel(const int* __restrict__ csum,
                             int* __restrict__ coff,
                             int* __restrict__ row_start) {
    if (threadIdx.x == 0 && blockIdx.x == 0) {
        int run = 0;
        for (int b = 0; b < NCHUNK; ++b) { coff[b] = run; run += csum[b]; }
        row_start[V_N] = run;
    }
}

// ---------------- Step 2c: per-chunk exclusive scan + chunk offset (R2 inner loop) ------
__global__ __launch_bounds__(1024) void scanC_kernel(const int* __restrict__ count,
                                                     const int* __restrict__ coff,
                                                     int* __restrict__ row_start,
                                                     int* __restrict__ cursor) {
    __shared__ int sdata[1024];
    int tid = threadIdx.x;
    int i = blockIdx.x * 1024 + tid;
    int v = (i < V_N) ? count[i] : 0;
    sdata[tid] = v;
    __syncthreads();
    for (int off = 1; off < 1024; off <<= 1) {
        int t = (tid >= off) ? sdata[tid - off] : 0;
        __syncthreads();
        sdata[tid] += t;
        __syncthreads();
    }
    int exc = sdata[tid] - v + coff[blockIdx.x];
    if (i < V_N) { row_start[i] = exc; cursor[i] = exc; }
}

// ---------------- Step 3: scatter nnz into row-sorted order (R2-verified) ----------------
__global__ __launch_bounds__(256) void scatter_kernel(const int* __restrict__ rows,
                                                      const int* __restrict__ cols,
                                                      const float* __restrict__ vals,
                                                      int* __restrict__ cursor,
                                                      int* __restrict__ sorted_colp,
                                                      float* __restrict__ sorted_val) {
    int n = blockIdx.x * blockDim.x + threadIdx.x;
    if (n >= NNZ_T) return;
    int a = n / NNZ_N;
    int r = rows[n];
    int pos = atomicAdd(&cursor[r], 1);
    sorted_colp[pos] = a * V_N + cols[n];
    sorted_val[pos] = vals[n];
}

// ---------------- Step 4: segmented accumulate -> h_sum f32 [V][128] (R2/R5-verified) ----
__global__ __launch_bounds__(256) void accum_kernel(const int* __restrict__ row_start,
                                                    const int* __restrict__ sorted_colp,
                                                    const float* __restrict__ sorted_val,
                                                    const float* __restrict__ W,
                                                    float* __restrict__ h_sum) {
    long long gid = (long long)blockIdx.x * blockDim.x + threadIdx.x;
    if (gid >= (long long)V_N * 32) return;
    int row = (int)(gid >> 5);
    int chunk = (int)(gid & 31);
    int s = row_start[row];
    int e = row_start[row + 1];
    float4 acc = make_float4(0.f, 0.f, 0.f, 0.f);
    for (int i = s; i < e; ++i) {
        int cp = sorted_colp[i];
        float v = sorted_val[i];
        const float4 w = *reinterpret_cast<const float4*>(
            W + (long long)cp * H_N + chunk * 4);
        acc.x += v * w.x;
        acc.y += v * w.y;
        acc.z += v * w.z;
        acc.w += v * w.w;
    }
    *reinterpret_cast<float4*>(h_sum + (long long)row * H_N + chunk * 4) = acc;
}

// ---------------- Step 5: fold fcW -> hw_t bf16 [16][KPAD] (k-major) ----------------
__global__ __launch_bounds__(256) void hw_kernel(const float* __restrict__ h_sum,
                                                 const float* __restrict__ fcW,
                                                 short* __restrict__ hw_t) {
    int idx = blockIdx.x * blockDim.x + threadIdx.x;   // v*16 + o
    if (idx >= V_N * O_N) return;
    int v = idx >> 4, o = idx & 15;
    const float* hrow = h_sum + (size_t)v * H_N;
    float s = 0.f;
#pragma unroll
    for (int h = 0; h < H_N; ++h) s += hrow[h] * fcW[h * O_N + o];
    hw_t[(size_t)o * KPAD + v] = (short)f2bf(s);
}

// ---------------- Step 6: init out with bias ----------------
__global__ __launch_bounds__(256) void init_out_kernel(const float* __restrict__ fcb,
                                                       float* __restrict__ out) {
    int idx = blockIdx.x * blockDim.x + threadIdx.x;
    if (idx >= M_N * O_N) return;
    out[idx] = fcb[idx & 15];
}

// ---------------- Step 7: streaming MFMA GEMM out += X @ hw_t^T, no LDS, no barriers ----
// grid (M_N/64 = 32, KSPL = 32), 256 thr = 4 waves; wave w: rows row0 = bx*64 + w*16
__global__ __launch_bounds__(256) void gemm_mfma4(const float* __restrict__ X,
                                                  const short* __restrict__ hw_t,
                                                  float* __restrict__ out) {
    const int tid = threadIdx.x;
    const int w = tid >> 6;
    const int lane = tid & 63;
    const int l15 = lane & 15;
    const int kg = lane >> 4;       // 0..3
    const int row0 = blockIdx.x * 64 + w * 16;
    const int k0 = blockIdx.y * KC;

    const float* xrow = X + (size_t)(row0 + l15) * V_N;   // A row (R5/R6-verified frag)
    const short* hrow = hw_t + (size_t)l15 * KPAD;        // B col (R6-verified frag)

    f32x4_t acc = {};

#pragma unroll 2
    for (int kb = k0; kb < k0 + KC; kb += 32) {
        int k = kb + kg * 8;
        float a[8];
        if (k + 7 < V_N) {
            const float2* p = reinterpret_cast<const float2*>(xrow + k);  // 8B-aligned always
            float2 u0 = p[0], u1 = p[1], u2 = p[2], u3 = p[3];
            a[0] = u0.x; a[1] = u0.y; a[2] = u1.x; a[3] = u1.y;
            a[4] = u2.x; a[5] = u2.y; a[6] = u3.x; a[7] = u3.y;
        } else {
#pragma unroll
            for (int j = 0; j < 8; ++j) a[j] = (k + j < V_N) ? xrow[k + j] : 0.f;
        }
        bf16x8_t av;
#pragma unroll
        for (int j = 0; j < 8; ++j) av[j] = (short)f2bf(a[j]);
        bf16x8_t bv = *reinterpret_cast<const bf16x8_t*>(hrow + k);  // zero-padded past V_N
        acc = __builtin_amdgcn_mfma_f32_16x16x32_bf16(av, bv, acc, 0, 0, 0);
    }

    // D layout (R5/R6-verified): col = l15 (output o), row = kg*4 + r4
#pragma unroll
    for (int r4 = 0; r4 < 4; ++r4)
        atomicAdd(&out[(size_t)(row0 + kg * 4 + r4) * O_N + l15], acc[r4]);
}

extern "C" void kernel_launch(void* const* d_in, const int* in_sizes, int n_in,
                              void* d_out, int out_size, void* d_ws, size_t ws_size,
                              hipStream_t stream) {
    const float* x    = (const float*)d_in[0];
    const int* rows   = (const int*)d_in[1];
    const int* cols   = (const int*)d_in[2];
    const float* vals = (const float*)d_in[3];
    const float* W    = (const float*)d_in[4];
    const float* fcW  = (const float*)d_in[5];
    const float* fcb  = (const float*)d_in[6];
    float* out = (float*)d_out;

    // ws layout, no aliasing: h_sum 15.63MB | hw_t 0.98MB | CSR 4.37MB  => ~21 MB
    char* base = (char*)d_ws;
    size_t off = 0;
    auto alloc = [&](size_t bytes) { size_t p = off; off = (off + bytes + 255) & ~(size_t)255; return p; };
    size_t o_hsum   = alloc((size_t)V_N * H_N * 4);
    size_t o_hwt    = alloc((size_t)O_N * KPAD * 2);
    size_t o_count  = alloc((size_t)V_N * 4);
    size_t o_rstart = alloc((size_t)(V_N + 1) * 4);
    size_t o_cursor = alloc((size_t)V_N * 4);
    size_t o_scolp  = alloc((size_t)NNZ_T * 4);
    size_t o_sval   = alloc((size_t)NNZ_T * 4);
    size_t o_csum   = alloc((size_t)NCHUNK * 4);
    size_t o_coff   = alloc((size_t)NCHUNK * 4);

    float* h_sum      = (float*)(base + o_hsum);
    short* hw_t       = (short*)(base + o_hwt);
    int*   count      = (int*)(base + o_count);
    int*   row_start  = (int*)(base + o_rstart);
    int*   cursor     = (int*)(base + o_cursor);
    int*   sorted_colp= (int*)(base + o_scolp);
    float* sorted_val = (float*)(base + o_sval);
    int*   csum       = (int*)(base + o_csum);
    int*   coff       = (int*)(base + o_coff);

    hipMemsetAsync(count, 0, (size_t)V_N * 4, stream);
    hipMemsetAsync(hw_t, 0, (size_t)O_N * KPAD * 2, stream);   // zero K-pad

    hist_kernel<<<(NNZ_T + 255) / 256, 256, 0, stream>>>(rows, count);
    scanA_kernel<<<NCHUNK, 1024, 0, stream>>>(count, csum);
    scanB_kernel<<<1, 64, 0, stream>>>(csum, coff, row_start);
    scanC_kernel<<<NCHUNK, 1024, 0, stream>>>(count, coff, row_start, cursor);
    scatter_kernel<<<(NNZ_T + 255) / 256, 256, 0, stream>>>(rows, cols, vals, cursor,
                                                            sorted_colp, sorted_val);
    {
        long long total = (long long)V_N * 32;
        accum_kernel<<<(int)((total + 255) / 256), 256, 0, stream>>>(
            row_start, sorted_colp, sorted_val, W, h_sum);
    }
    hw_kernel<<<(V_N * O_N + 255) / 256, 256, 0, stream>>>(h_sum, fcW, hw_t);

    init_out_kernel<<<(M_N * O_N + 255) / 256, 256, 0, stream>>>(fcb, out);
    gemm_mfma4<<<dim3(M_N / 64, KSPL), 256, 0, stream>>>(x, hw_t, out);
}

// Round 8
// 177.596 us; speedup vs baseline: 6.4202x; 1.1236x over previous
//
#include <hip/hip_runtime.h>

#define V_N 30522
#define A_N 2
#define H_N 128
#define O_N 16
#define NNZ_N 250000
#define NNZ_T (A_N * NNZ_N)  // 500000
#define M_N 2048
#define AV_N (A_N * V_N)     // 61044

#define KPAD 30720
#define KSPL 32
#define KC (KPAD / KSPL)     // 960 = 30 steps of 32
#define NCHUNK 30            // ceil(V_N / 1024)

typedef __attribute__((ext_vector_type(8))) short bf16x8_t;
typedef __attribute__((ext_vector_type(4))) float f32x4_t;

static __device__ __forceinline__ unsigned short f2bf(float f) {
    union { float f; unsigned u; } v; v.f = f;
    unsigned r = v.u + 0x7fffu + ((v.u >> 16) & 1u);   // RNE
    return (unsigned short)(r >> 16);
}

// ---------------- Step 0: wfc[a*V+v][16] = W[a][v][:] @ fcW  (f32) ----------------
__global__ __launch_bounds__(256) void wfc_kernel(const float* __restrict__ W,
                                                  const float* __restrict__ fcW,
                                                  float* __restrict__ wfc) {
    __shared__ float wrow[16][128];
    int row0 = blockIdx.x * 16;
    for (int idx = threadIdx.x; idx < 16 * 32; idx += 256) {
        int r = idx >> 5, c4 = (idx & 31) * 4;
        int grow = row0 + r;
        float4 v = make_float4(0.f, 0.f, 0.f, 0.f);
        if (grow < AV_N)
            v = *reinterpret_cast<const float4*>(W + (size_t)grow * H_N + c4);
        *reinterpret_cast<float4*>(&wrow[r][c4]) = v;
    }
    __syncthreads();
    int r = threadIdx.x >> 4, o = threadIdx.x & 15;
    int grow = row0 + r;
    if (grow >= AV_N) return;
    float s = 0.f;
#pragma unroll
    for (int h = 0; h < H_N; ++h) s += wrow[r][h] * fcW[h * O_N + o];
    wfc[(size_t)grow * O_N + o] = s;
}

// ---------------- Step 1: histogram of row indices (R2-verified) ----------------
__global__ __launch_bounds__(256) void hist_kernel(const int* __restrict__ rows,
                                                   int* __restrict__ count) {
    int n = blockIdx.x * blockDim.x + threadIdx.x;
    if (n >= NNZ_T) return;
    atomicAdd(&count[rows[n]], 1);
}

// ---------------- Step 2a: per-1024-chunk sums (R7-verified) ----------------
__global__ __launch_bounds__(1024) void scanA_kernel(const int* __restrict__ count,
                                                     int* __restrict__ csum) {
    __shared__ int sdata[1024];
    int tid = threadIdx.x;
    int i = blockIdx.x * 1024 + tid;
    sdata[tid] = (i < V_N) ? count[i] : 0;
    __syncthreads();
    for (int off = 512; off > 0; off >>= 1) {
        if (tid < off) sdata[tid] += sdata[tid + off];
        __syncthreads();
    }
    if (tid == 0) csum[blockIdx.x] = sdata[0];
}

// ---------------- Step 2b: scan chunk sums (R7-verified) ----------------
__global__ void scanB_kernel(const int* __restrict__ csum,
                             int* __restrict__ coff,
                             int* __restrict__ row_start) {
    if (threadIdx.x == 0 && blockIdx.x == 0) {
        int run = 0;
        for (int b = 0; b < NCHUNK; ++b) { coff[b] = run; run += csum[b]; }
        row_start[V_N] = run;
    }
}

// ---------------- Step 2c: per-chunk exclusive scan + offset (R7-verified) ----------------
__global__ __launch_bounds__(1024) void scanC_kernel(const int* __restrict__ count,
                                                     const int* __restrict__ coff,
                                                     int* __restrict__ row_start,
                                                     int* __restrict__ cursor) {
    __shared__ int sdata[1024];
    int tid = threadIdx.x;
    int i = blockIdx.x * 1024 + tid;
    int v = (i < V_N) ? count[i] : 0;
    sdata[tid] = v;
    __syncthreads();
    for (int off = 1; off < 1024; off <<= 1) {
        int t = (tid >= off) ? sdata[tid - off] : 0;
        __syncthreads();
        sdata[tid] += t;
        __syncthreads();
    }
    int exc = sdata[tid] - v + coff[blockIdx.x];
    if (i < V_N) { row_start[i] = exc; cursor[i] = exc; }
}

// ---------------- Step 3: scatter nnz, packed (colp,val) 8B stores ----------------
__global__ __launch_bounds__(256) void scatter_kernel(const int* __restrict__ rows,
                                                      const int* __restrict__ cols,
                                                      const float* __restrict__ vals,
                                                      int* __restrict__ cursor,
                                                      unsigned long long* __restrict__ scv) {
    int n = blockIdx.x * blockDim.x + threadIdx.x;
    if (n >= NNZ_T) return;
    int a = n / NNZ_N;
    int r = rows[n];
    int pos = atomicAdd(&cursor[r], 1);
    union { float f; unsigned u; } uv; uv.f = vals[n];
    scv[pos] = ((unsigned long long)uv.u << 32) | (unsigned)(a * V_N + cols[n]);
}

// ---------------- Step 4: segmented accumulate -> hw_t bf16 [16][KPAD] ----------------
// thread = row*16 + o; gathers 16-wide wfc rows (64B/nnz), writes hw_t k-major.
__global__ __launch_bounds__(256) void accum_hw_kernel(const int* __restrict__ row_start,
                                                       const unsigned long long* __restrict__ scv,
                                                       const float* __restrict__ wfc,
                                                       short* __restrict__ hw_t) {
    int gid = blockIdx.x * blockDim.x + threadIdx.x;
    if (gid >= V_N * O_N) return;
    int row = gid >> 4, o = gid & 15;
    int s = row_start[row];
    int e = row_start[row + 1];
    float acc = 0.f;
    for (int i = s; i < e; ++i) {
        unsigned long long cv = scv[i];
        int cp = (int)(cv & 0xffffffffu);
        union { unsigned u; float f; } uv; uv.u = (unsigned)(cv >> 32);
        acc += uv.f * wfc[(size_t)cp * O_N + o];
    }
    hw_t[(size_t)o * KPAD + row] = (short)f2bf(acc);
}

// ---------------- Step 5: init out with bias (R7-verified) ----------------
__global__ __launch_bounds__(256) void init_out_kernel(const float* __restrict__ fcb,
                                                       float* __restrict__ out) {
    int idx = blockIdx.x * blockDim.x + threadIdx.x;
    if (idx >= M_N * O_N) return;
    out[idx] = fcb[idx & 15];
}

// ---------------- Step 6: streaming MFMA GEMM (R7-verified, byte-identical) ----------
__global__ __launch_bounds__(256) void gemm_mfma4(const float* __restrict__ X,
                                                  const short* __restrict__ hw_t,
                                                  float* __restrict__ out) {
    const int tid = threadIdx.x;
    const int w = tid >> 6;
    const int lane = tid & 63;
    const int l15 = lane & 15;
    const int kg = lane >> 4;       // 0..3
    const int row0 = blockIdx.x * 64 + w * 16;
    const int k0 = blockIdx.y * KC;

    const float* xrow = X + (size_t)(row0 + l15) * V_N;
    const short* hrow = hw_t + (size_t)l15 * KPAD;

    f32x4_t acc = {};

#pragma unroll 2
    for (int kb = k0; kb < k0 + KC; kb += 32) {
        int k = kb + kg * 8;
        float a[8];
        if (k + 7 < V_N) {
            const float2* p = reinterpret_cast<const float2*>(xrow + k);
            float2 u0 = p[0], u1 = p[1], u2 = p[2], u3 = p[3];
            a[0] = u0.x; a[1] = u0.y; a[2] = u1.x; a[3] = u1.y;
            a[4] = u2.x; a[5] = u2.y; a[6] = u3.x; a[7] = u3.y;
        } else {
#pragma unroll
            for (int j = 0; j < 8; ++j) a[j] = (k + j < V_N) ? xrow[k + j] : 0.f;
        }
        bf16x8_t av;
#pragma unroll
        for (int j = 0; j < 8; ++j) av[j] = (short)f2bf(a[j]);
        bf16x8_t bv = *reinterpret_cast<const bf16x8_t*>(hrow + k);
        acc = __builtin_amdgcn_mfma_f32_16x16x32_bf16(av, bv, acc, 0, 0, 0);
    }

#pragma unroll
    for (int r4 = 0; r4 < 4; ++r4)
        atomicAdd(&out[(size_t)(row0 + kg * 4 + r4) * O_N + l15], acc[r4]);
}

extern "C" void kernel_launch(void* const* d_in, const int* in_sizes, int n_in,
                              void* d_out, int out_size, void* d_ws, size_t ws_size,
                              hipStream_t stream) {
    const float* x    = (const float*)d_in[0];
    const int* rows   = (const int*)d_in[1];
    const int* cols   = (const int*)d_in[2];
    const float* vals = (const float*)d_in[3];
    const float* W    = (const float*)d_in[4];
    const float* fcW  = (const float*)d_in[5];
    const float* fcb  = (const float*)d_in[6];
    float* out = (float*)d_out;

    // ws: wfc 3.91MB | hw_t 0.98MB | count/rstart/cursor 0.37MB | scv 4MB | csum/coff => ~9.3MB
    char* base = (char*)d_ws;
    size_t off = 0;
    auto alloc = [&](size_t bytes) { size_t p = off; off = (off + bytes + 255) & ~(size_t)255; return p; };
    size_t o_wfc    = alloc((size_t)AV_N * O_N * 4);
    size_t o_hwt    = alloc((size_t)O_N * KPAD * 2);
    size_t o_count  = alloc((size_t)V_N * 4);
    size_t o_rstart = alloc((size_t)(V_N + 1) * 4);
    size_t o_cursor = alloc((size_t)V_N * 4);
    size_t o_scv    = alloc((size_t)NNZ_T * 8);
    size_t o_csum   = alloc((size_t)NCHUNK * 4);
    size_t o_coff   = alloc((size_t)NCHUNK * 4);

    float* wfc        = (float*)(base + o_wfc);
    short* hw_t       = (short*)(base + o_hwt);
    int*   count      = (int*)(base + o_count);
    int*   row_start  = (int*)(base + o_rstart);
    int*   cursor     = (int*)(base + o_cursor);
    unsigned long long* scv = (unsigned long long*)(base + o_scv);
    int*   csum       = (int*)(base + o_csum);
    int*   coff       = (int*)(base + o_coff);

    hipMemsetAsync(count, 0, (size_t)V_N * 4, stream);
    hipMemsetAsync(hw_t, 0, (size_t)O_N * KPAD * 2, stream);   // zero K-pad

    wfc_kernel<<<(AV_N + 15) / 16, 256, 0, stream>>>(W, fcW, wfc);
    hist_kernel<<<(NNZ_T + 255) / 256, 256, 0, stream>>>(rows, count);
    scanA_kernel<<<NCHUNK, 1024, 0, stream>>>(count, csum);
    scanB_kernel<<<1, 64, 0, stream>>>(csum, coff, row_start);
    scanC_kernel<<<NCHUNK, 1024, 0, stream>>>(count, coff, row_start, cursor);
    scatter_kernel<<<(NNZ_T + 255) / 256, 256, 0, stream>>>(rows, cols, vals, cursor, scv);
    accum_hw_kernel<<<(V_N * O_N + 255) / 256, 256, 0, stream>>>(row_start, scv, wfc, hw_t);

    init_out_kernel<<<(M_N * O_N + 255) / 256, 256, 0, stream>>>(fcb, out);
    gemm_mfma4<<<dim3(M_N / 64, KSPL), 256, 0, stream>>>(x, hw_t, out);
}